// Round 4
// baseline (378.127 us; speedup 1.0000x reference)
//
#include <hip/hip_runtime.h>
#include <stdint.h>

// FLASH — R10: 256x256 pipelined 4-phase with 1-phase-lookahead register
//  prefetch.  R9's phase-locked {ds_read; barrier; MFMA; barrier} serialized
//  LDS streaming (768 cyc/tile/CU) against MFMA (512 cyc/tile/SIMD) ->
//  MfmaUtil 31%.  R10 issues each phase's fragment loads ONE PHASE EARLY so
//  LDS streams under the MFMA cluster (compiler emits counted lgkmcnt for the
//  in-flight loads; sched_barrier(0) pins load issue above the MFMA so loads
//  can't sink past a later stage into the same region).
//  Quadrant order (ms,ns): (0,0)->(1,0)->(0,1)->(1,1); last phase uses {a1,b1}
//  so {a0,b0} regs are free to prefetch tile t+1's first phase after the
//  vmcnt(8)+barrier.  Stages: A0,B0(t+2)@Ph2, A1@Ph3, B1@Ph4 — every region's
//  readers drained one phase + barrier earlier.  vmcnt ledger: 8 in flight,
//  drain 8/tile (vmcnt(8); vmcnt(0) on the tail tiles).  Barriers 4/tile.
//  LDS swizzle (unchanged, measured conflict-free): slot p of row r holds
//  chunk p ^ (r&7) ^ ((r>>3)&1), realized via pre-swizzled global source col.
//  Modes 1 (K=128) and 4 (N=128) stay on the old 128^2 kernel.

#define H_DIM  1024
#define E_DIM  2048
#define SD     128
#define B_SZ   4
#define S_LEN  2048
#define M_TOT  (B_SZ * S_LEN)          // 8192
#define F_DIM  (2 * E_DIM + SD)        // 4224

typedef _Float16 f16;
typedef __attribute__((ext_vector_type(4))) _Float16 f16x4;
typedef __attribute__((ext_vector_type(8))) _Float16 f16x8;
typedef __attribute__((ext_vector_type(16))) float f32x16;

__device__ __forceinline__ float silu_f(float x) { return x / (1.f + __expf(-x)); }

__device__ __forceinline__ void gload16(const void* g, void* l) {
  __builtin_amdgcn_global_load_lds(
      (const __attribute__((address_space(1))) void*)(uintptr_t)g,
      (__attribute__((address_space(3))) void*)(uint32_t)(uintptr_t)l,
      16, 0, 0);
}

// ---------------- prep kernels ----------------
__global__ __launch_bounds__(256) void cast_f16_k(const float* __restrict__ src,
                                                  f16* __restrict__ dst, long n) {
  long i = ((long)blockIdx.x * 256 + threadIdx.x) * 4;
  if (i < n) {
    float4 v = *(const float4*)(src + i);
    f16x4 h; h[0] = (f16)v.x; h[1] = (f16)v.y; h[2] = (f16)v.z; h[3] = (f16)v.w;
    *(f16x4*)(dst + i) = h;
  }
}

__global__ __launch_bounds__(256) void transpose_cast_k(const float* __restrict__ src,
                                                        f16* __restrict__ dst, int R, int C) {
  __shared__ float tile[32][33];
  int c0 = blockIdx.x * 32, r0 = blockIdx.y * 32;
  int tx = threadIdx.x & 31, ty = threadIdx.x >> 5;
  for (int i = ty; i < 32; i += 8) tile[i][tx] = src[(long)(r0 + i) * C + c0 + tx];
  __syncthreads();
  for (int i = ty; i < 32; i += 8) dst[(long)(c0 + i) * R + r0 + tx] = (f16)tile[tx][i];
}

// ---------------- 256x256 pipelined GEMM ----------------
// A: [m][k] f16 (row stride K), B: [n][k] f16 (row stride K).
//  MODE 0: K=1024, u/v epilogue.  MODE 2: K=2048, p = u*(sq@v^T).
//  MODE 3: K=2048, out fp32 = acc*2^-34 + b_out.
template <int MODE>
__global__ __launch_bounds__(512, 2) void gemm256(
    const f16* __restrict__ Ag, const f16* __restrict__ Bg,
    float* __restrict__ F0, f16* __restrict__ O0, f16* __restrict__ O1,
    const f16* __restrict__ I0, const float* __restrict__ C0)
{
  constexpr int K  = (MODE == 0) ? H_DIM : 2048;
  constexpr int NT = K / 64;

  __shared__ f16 As[2][256][64];   // 64 KB
  __shared__ f16 Bs[2][256][64];   // 64 KB

  const int t    = threadIdx.x;
  const int w    = t >> 6;            // 0..7
  const int lane = t & 63;
  const int lo5  = lane & 31;
  const int hi   = lane >> 5;
  const int wm   = w >> 2;            // 0..1
  const int wn   = w & 3;             // 0..3

  // T1: bijective XCD swizzle (nwg % 8 == 0 for all modes)
  const int gx  = gridDim.x;
  const int nwg = gx * gridDim.y;
  const int lin = blockIdx.y * gx + blockIdx.x;
  const int cpx = nwg >> 3;
  const int wg  = (lin & 7) * cpx + (lin >> 3);
  const int n0  = (wg % gx) * 256;
  const int m0  = (wg / gx) * 256;
  const long z  = blockIdx.z;

  const f16* A = Ag + (MODE == 2 ? z * (long)S_LEN * S_LEN : 0);
  const f16* B = Bg + (MODE == 2 ? z * (long)E_DIM * S_LEN : 0);

  // stage one half-tile (128 rows x 64 k): 2 x gload16 per thread.
  // LDS dst linear; global column pre-swizzled:
  //   logical chunk = (lane&7) ^ (lane>>3) ^ (grp&1)   [= p ^ (r&7) ^ ((r>>3)&1)]
  auto stageA = [&](int bb, int half, int kt2) {
    const f16* g0 = A + (long)(m0 + half * 128) * K + kt2 * 64;
    f16* lb = &As[bb][half * 128][0];
#pragma unroll
    for (int j = 0; j < 2; j++) {
      int grp = (j << 3) + w;                       // 0..15
      int rl  = (grp << 3) + (lane >> 3);           // 0..127
      gload16(g0 + (long)rl * K + (((lane & 7) ^ (lane >> 3) ^ (grp & 1)) << 3),
              lb + (grp << 9));
    }
  };
  auto stageB = [&](int bb, int half, int kt2) {
    const f16* g0 = B + (long)(n0 + half * 128) * K + kt2 * 64;
    f16* lb = &Bs[bb][half * 128][0];
#pragma unroll
    for (int j = 0; j < 2; j++) {
      int grp = (j << 3) + w;
      int rl  = (grp << 3) + (lane >> 3);
      gload16(g0 + (long)rl * K + (((lane & 7) ^ (lane >> 3) ^ (grp & 1)) << 3),
              lb + (grp << 9));
    }
  };

  // acc[q]: q = ms*2 + ns
  f32x16 acc[4][2] = {};
  f16x8 a0[2][4], a1[2][4], b0[4], b1[4];

  const int swz = (lo5 & 7) ^ ((lo5 >> 3) & 1);   // reader row-swizzle term
  const int rA  = wm * 64 + lo5;
  const int rB  = wn * 32 + lo5;

  auto loadA0 = [&](int bb) {
#pragma unroll
    for (int k = 0; k < 4; k++) {
      const int pc = ((((k << 1) + hi) ^ swz) << 3);
      a0[0][k] = *(const f16x8*)&As[bb][rA][pc];
      a0[1][k] = *(const f16x8*)&As[bb][rA + 32][pc];
    }
  };
  auto loadA1 = [&](int bb) {
#pragma unroll
    for (int k = 0; k < 4; k++) {
      const int pc = ((((k << 1) + hi) ^ swz) << 3);
      a1[0][k] = *(const f16x8*)&As[bb][128 + rA][pc];
      a1[1][k] = *(const f16x8*)&As[bb][128 + rA + 32][pc];
    }
  };
  auto loadB0 = [&](int bb) {
#pragma unroll
    for (int k = 0; k < 4; k++) {
      const int pc = ((((k << 1) + hi) ^ swz) << 3);
      b0[k] = *(const f16x8*)&Bs[bb][rB][pc];
    }
  };
  auto loadB1 = [&](int bb) {
#pragma unroll
    for (int k = 0; k < 4; k++) {
      const int pc = ((((k << 1) + hi) ^ swz) << 3);
      b1[k] = *(const f16x8*)&Bs[bb][128 + rB][pc];
    }
  };

#define MMA(Q, AV, BV) do {                                                      \
    __builtin_amdgcn_s_setprio(1);                                               \
    _Pragma("unroll")                                                            \
    for (int k_ = 0; k_ < 4; k_++) {                                             \
      acc[Q][0] = __builtin_amdgcn_mfma_f32_32x32x16_f16(AV[0][k_], BV[k_],      \
                                                         acc[Q][0], 0, 0, 0);    \
      acc[Q][1] = __builtin_amdgcn_mfma_f32_32x32x16_f16(AV[1][k_], BV[k_],      \
                                                         acc[Q][1], 0, 0, 0);    \
    }                                                                            \
    __builtin_amdgcn_s_setprio(0);                                               \
  } while (0)

  // prologue: stage tile0 (buf0) and tile1 (buf1) fully; wait tile0; barrier;
  // prefetch tile0's first-phase fragments (a0,b0).
  stageA(0, 0, 0); stageA(0, 1, 0); stageB(0, 0, 0); stageB(0, 1, 0);
  stageA(1, 0, 1); stageA(1, 1, 1); stageB(1, 0, 1); stageB(1, 1, 1);
  asm volatile("s_waitcnt vmcnt(8)" ::: "memory");
  __builtin_amdgcn_s_barrier();
  loadA0(0); loadB0(0);

  for (int kt = 0; kt < NT; ++kt) {
    const int bf = kt & 1;
    const bool s2    = (kt + 2 < NT);
    const bool lastt = (kt + 1 == NT);

    // ---- Ph1 (0,0): prefetch a1; MFMA a0·b0
    loadA1(bf);
    __builtin_amdgcn_sched_barrier(0);
    MMA(0, a0, b0);
    __builtin_amdgcn_s_barrier();

    // ---- Ph2 (1,0): stage t+2:A0,B0; prefetch b1; MFMA a1·b0
    if (s2) { stageA(bf, 0, kt + 2); stageB(bf, 0, kt + 2); }
    loadB1(bf);
    __builtin_amdgcn_sched_barrier(0);
    MMA(2, a1, b0);
    __builtin_amdgcn_s_barrier();

    // ---- Ph3 (0,1): stage t+2:A1; MFMA a0·b1
    if (s2) stageA(bf, 1, kt + 2);
    MMA(1, a0, b1);
    __builtin_amdgcn_s_barrier();

    // ---- Ph4 (1,1): stage t+2:B1; drain t+1; prefetch t+1's a0,b0; MFMA a1·b1
    if (s2) stageB(bf, 1, kt + 2);
    if (s2) { asm volatile("s_waitcnt vmcnt(8)" ::: "memory"); }
    else    { asm volatile("s_waitcnt vmcnt(0)" ::: "memory"); }
    __builtin_amdgcn_s_barrier();
    if (!lastt) { loadA0(bf ^ 1); loadB0(bf ^ 1); }
    __builtin_amdgcn_sched_barrier(0);
    MMA(3, a1, b1);
  }
#undef MMA

  // C/D (32x32): col = lane&31, row = (reg&3) + 8*(reg>>2) + 4*hi
#pragma unroll
  for (int q = 0; q < 4; q++) {
    const int ms = q >> 1;
    const int ns = q & 1;
#pragma unroll
    for (int im = 0; im < 2; im++) {
      const int gc    = n0 + ns * 128 + wn * 32 + lo5;
      const int rbase = m0 + ms * 128 + wm * 64 + im * 32 + (hi << 2);
      if (MODE == 0) {
        const float bias = C0[gc];
        if (n0 < E_DIM) {            // u region: fp16 row-major [M][E]
#pragma unroll
          for (int g = 0; g < 4; g++)
#pragma unroll
            for (int rr = 0; rr < 4; rr++) {
              int gr = rbase + (g << 3) + rr;
              O0[(long)gr * E_DIM + gc] = (f16)silu_f(acc[q][im][g * 4 + rr] + bias);
            }
        } else {                     // v region: fp16 transposed [b][e][s]
#pragma unroll
          for (int g = 0; g < 4; g++) {
            int gr0 = rbase + (g << 3);
            int b   = gr0 >> 11;
            int s0  = gr0 & (S_LEN - 1);
            f16x4 pk;
#pragma unroll
            for (int rr = 0; rr < 4; rr++) pk[rr] = (f16)silu_f(acc[q][im][g * 4 + rr] + bias);
            *(f16x4*)&O1[((long)b * E_DIM + (gc - E_DIM)) * S_LEN + s0] = pk;
          }
        }
      } else if (MODE == 2) {        // p = fp16(u * attn_v_scaled)
        const long rowoff = z * S_LEN;
#pragma unroll
        for (int g = 0; g < 4; g++)
#pragma unroll
          for (int rr = 0; rr < 4; rr++) {
            int gr = rbase + (g << 3) + rr;
            long idx = (rowoff + gr) * (long)E_DIM + gc;
            O0[idx] = (f16)((float)I0[idx] * acc[q][im][g * 4 + rr]);
          }
      } else {                       // MODE 3: out = acc*2^-34 + b_out (fp32)
        const float bias = C0[gc];
#pragma unroll
        for (int g = 0; g < 4; g++)
#pragma unroll
          for (int rr = 0; rr < 4; rr++) {
            int gr = rbase + (g << 3) + rr;
            F0[(long)gr * H_DIM + gc] = acc[q][im][g * 4 + rr] * (1.0f / 17179869184.0f) + bias;
          }
      }
    }
  }
}

// ---------------- old 128x128 kernel (modes 1 and 4 only) ----------------
template <int MODE>
__global__ __launch_bounds__(256) void mfma_gemm(
    const f16* __restrict__ Ag, const f16* __restrict__ Bg,
    float* __restrict__ F0, f16* __restrict__ H0, const f16* __restrict__ H1,
    f16* __restrict__ H2, f16* __restrict__ H3,
    const float* __restrict__ C0, const float* __restrict__ C1,
    const float* __restrict__ C2)
{
  constexpr int K   = (MODE == 1) ? SD : H_DIM;
  constexpr int LDA = K, LDB = K;

  __shared__ f16 As[2][128][32];
  __shared__ f16 Bs[2][128][32];

  const int t    = threadIdx.x;
  const int w    = t >> 6;
  const int lane = t & 63;
  const int lo5  = lane & 31;
  const int hi   = lane >> 5;
  const int wy   = w >> 1, wx = w & 1;
  const int m0   = blockIdx.y * 128;
  const int n0   = blockIdx.x * 128;
  const long z   = blockIdx.z;

  const f16* A = Ag + (MODE == 1 ? z * (long)S_LEN * SD : 0);
  const f16* B = Bg + (MODE == 1 ? z * (long)S_LEN * SD : 0);

  const int srow = lane >> 2;
  const int scol = (((lane & 3) ^ ((srow >> 1) & 3))) * 8;
  const int rsw  = (lo5 >> 1) & 3;

  f32x16 acc[2][2] = {};

  for (int k0 = 0; k0 < K; k0 += 64) {
#pragma unroll
    for (int h = 0; h < 2; h++)
#pragma unroll
      for (int g16 = 0; g16 < 2; g16++) {
        const int r = (w << 5) + (g16 << 4);
        gload16(A + (long)(m0 + r + srow) * LDA + k0 + (h << 5) + scol, &As[h][r][0]);
        gload16(B + (long)(n0 + r + srow) * LDB + k0 + (h << 5) + scol, &Bs[h][r][0]);
      }
    __syncthreads();

#pragma unroll
    for (int ks = 0; ks < 4; ks++) {
      const int h  = ks >> 1;
      const int cl = ((ks & 1) << 1) + hi;
      const int kc = (cl ^ rsw) << 3;
      f16x8 av[2], bv[2];
#pragma unroll
      for (int i = 0; i < 2; i++)
        av[i] = *(const f16x8*)&As[h][(wy << 6) + (i << 5) + lo5][kc];
#pragma unroll
      for (int j = 0; j < 2; j++)
        bv[j] = *(const f16x8*)&Bs[h][(wx << 6) + (j << 5) + lo5][kc];
#pragma unroll
      for (int i = 0; i < 2; i++)
#pragma unroll
        for (int j = 0; j < 2; j++)
          acc[i][j] = __builtin_amdgcn_mfma_f32_32x32x16_f16(av[i], bv[j], acc[i][j], 0, 0, 0);
    }
    __syncthreads();
  }

  const int rb0 = m0 + (wy << 6) + (hi << 2);
  const int cb0 = n0 + (wx << 6) + lo5;

  if (MODE == 4) {                    // q,k from base cols (N=128)
#pragma unroll
    for (int i = 0; i < 2; i++)
#pragma unroll
      for (int j = 0; j < 2; j++) {
        int jj = cb0 + (j << 5);
        float bias = C0[jj];
        float g0 = C1[jj], g1 = C1[SD + jj];
        float be0 = C2[jj], be1 = C2[SD + jj];
#pragma unroll
        for (int g = 0; g < 4; g++)
#pragma unroll
          for (int rr = 0; rr < 4; rr++) {
            int gr = rb0 + (i << 5) + (g << 3) + rr;
            float s = silu_f(acc[i][j][g * 4 + rr] + bias);
            H2[(long)gr * SD + jj] = (f16)(s * g0 + be0);
            H3[(long)gr * SD + jj] = (f16)(s * g1 + be1);
          }
      }
  } else {                            // MODE 1: sq = (relu(q·k)*64)^2
#pragma unroll
    for (int i = 0; i < 2; i++)
#pragma unroll
      for (int j = 0; j < 2; j++) {
        int gc = cb0 + (j << 5);
#pragma unroll
        for (int g = 0; g < 4; g++)
#pragma unroll
          for (int rr = 0; rr < 4; rr++) {
            int gr = rb0 + (i << 5) + (g << 3) + rr;
            float tv = fmaxf(acc[i][j][g * 4 + rr], 0.f) * 64.f;
            H0[z * (long)S_LEN * S_LEN + (long)gr * S_LEN + gc] = (f16)(tv * tv);
          }
      }
  }
}

extern "C" void kernel_launch(void* const* d_in, const int* in_sizes, int n_in,
                              void* d_out, int out_size, void* d_ws, size_t ws_size,
                              hipStream_t stream) {
  const float* X     = (const float*)d_in[0];
  const float* W_uv  = (const float*)d_in[1];
  const float* b_uv  = (const float*)d_in[2];
  const float* gamma = (const float*)d_in[3];
  const float* beta  = (const float*)d_in[4];
  const float* W_out = (const float*)d_in[5];
  const float* b_out = (const float*)d_in[6];
  float* out = (float*)d_out;

  char* wp = (char*)d_ws;
  f16* Xh   = (f16*)wp; wp += (long)M_TOT * H_DIM * 2;
  f16* Wuvt = (f16*)wp; wp += (long)F_DIM * H_DIM * 2;
  f16* Wt   = (f16*)wp; wp += (long)H_DIM * E_DIM * 2;
  f16* u    = (f16*)wp; wp += (long)M_TOT * E_DIM * 2;
  f16* vt   = (f16*)wp; wp += (long)M_TOT * E_DIM * 2;
  f16* qh   = (f16*)wp; wp += (long)M_TOT * SD * 2;
  f16* kh   = (f16*)wp; wp += (long)M_TOT * SD * 2;
  f16* sq   = (f16*)wp; wp += (long)B_SZ * S_LEN * S_LEN * 2;
  f16* p    = (f16*)wp; wp += (long)M_TOT * E_DIM * 2;

  // prep
  cast_f16_k<<<(M_TOT * H_DIM) / (256 * 4), 256, 0, stream>>>(X, Xh, (long)M_TOT * H_DIM);
  transpose_cast_k<<<dim3(F_DIM / 32, H_DIM / 32), 256, 0, stream>>>(W_uv, Wuvt, H_DIM, F_DIM);
  transpose_cast_k<<<dim3(H_DIM / 32, E_DIM / 32), 256, 0, stream>>>(W_out, Wt, E_DIM, H_DIM);

  // u, v_t  (M=8192, N=4096, K=1024) — 256² pipelined
  gemm256<0><<<dim3(2 * E_DIM / 256, M_TOT / 256, 1), 512, 0, stream>>>(
      Xh, Wuvt, nullptr, u, vt, nullptr, b_uv);

  // q, k (base 128 cols)
  mfma_gemm<4><<<dim3(1, M_TOT / 128, 1), 256, 0, stream>>>(
      Xh, Wuvt + (long)2 * E_DIM * H_DIM, nullptr, nullptr, nullptr, qh, kh,
      b_uv + 2 * E_DIM, gamma, beta);

  // sq = (relu(q@k^T)*2^6)^2
  mfma_gemm<1><<<dim3(S_LEN / 128, S_LEN / 128, B_SZ), 256, 0, stream>>>(
      qh, kh, nullptr, sq, nullptr, nullptr, nullptr, nullptr, nullptr, nullptr);

  // p = u * (sq @ v)  (M=2048/batch, N=2048, K=2048) — 256² pipelined
  gemm256<2><<<dim3(E_DIM / 256, S_LEN / 256, B_SZ), 512, 0, stream>>>(
      sq, vt, nullptr, p, nullptr, u, nullptr);

  // out = p @ W_out * 2^-34 + b_out  (M=8192, N=1024, K=2048) — 256² pipelined
  gemm256<3><<<dim3(H_DIM / 256, M_TOT / 256, 1), 512, 0, stream>>>(
      p, Wt, out, nullptr, nullptr, nullptr, b_out);
}

// Round 5
// 369.929 us; speedup vs baseline: 1.0222x; 1.0222x over previous
//
#include <hip/hip_runtime.h>
#include <stdint.h>

// FLASH — R11: 256x256, 4 phases/K-tile, ONE barrier per phase, balanced MFMA.
//  R10 post-mortem: sched_barrier(0) order-pinning (m141 failure mode) + stage
//  reorder regressed; reverted.  R11 = R9 with two changes:
//   (a) mid-phase barrier removed (8 -> 4 barriers/tile).  Safety: stage(p)
//       overwrites only regions whose readers ran in p-1; end-barrier(p-1) +
//       compiler lgkmcnt-before-MFMA already guarantees those reads completed.
//   (b) MFMA redistributed 4/8/8/12 against reads 12/4/8/0 so read-heavy and
//       MFMA-heavy phases are adjacent -> cross-wave skew can overlap the P1
//       read burst with P4 MFMA tails (the only overlap mechanism at
//       1 block/CU; 2 blocks cannot fit the 128-VGPR accumulators).
//  Staging (= R9): P2: A0,B0(t+2); P3: B1; P4: A1; vmcnt(8) at P4 (drains
//  exactly tile t+1; t+2's 8 loads stay in flight).  Never vmcnt(0) mid-loop.
//  LDS swizzle (measured conflict-free, R9): slot p of row r holds chunk
//  p ^ (r&7) ^ ((r>>3)&1), realized via pre-swizzled global source column.
//  Modes 1 (K=128) and 4 (N=128) stay on the old 128^2 kernel.

#define H_DIM  1024
#define E_DIM  2048
#define SD     128
#define B_SZ   4
#define S_LEN  2048
#define M_TOT  (B_SZ * S_LEN)          // 8192
#define F_DIM  (2 * E_DIM + SD)        // 4224

typedef _Float16 f16;
typedef __attribute__((ext_vector_type(4))) _Float16 f16x4;
typedef __attribute__((ext_vector_type(8))) _Float16 f16x8;
typedef __attribute__((ext_vector_type(16))) float f32x16;

__device__ __forceinline__ float silu_f(float x) { return x / (1.f + __expf(-x)); }

__device__ __forceinline__ void gload16(const void* g, void* l) {
  __builtin_amdgcn_global_load_lds(
      (const __attribute__((address_space(1))) void*)(uintptr_t)g,
      (__attribute__((address_space(3))) void*)(uint32_t)(uintptr_t)l,
      16, 0, 0);
}

// ---------------- prep kernels ----------------
__global__ __launch_bounds__(256) void cast_f16_k(const float* __restrict__ src,
                                                  f16* __restrict__ dst, long n) {
  long i = ((long)blockIdx.x * 256 + threadIdx.x) * 4;
  if (i < n) {
    float4 v = *(const float4*)(src + i);
    f16x4 h; h[0] = (f16)v.x; h[1] = (f16)v.y; h[2] = (f16)v.z; h[3] = (f16)v.w;
    *(f16x4*)(dst + i) = h;
  }
}

__global__ __launch_bounds__(256) void transpose_cast_k(const float* __restrict__ src,
                                                        f16* __restrict__ dst, int R, int C) {
  __shared__ float tile[32][33];
  int c0 = blockIdx.x * 32, r0 = blockIdx.y * 32;
  int tx = threadIdx.x & 31, ty = threadIdx.x >> 5;
  for (int i = ty; i < 32; i += 8) tile[i][tx] = src[(long)(r0 + i) * C + c0 + tx];
  __syncthreads();
  for (int i = ty; i < 32; i += 8) dst[(long)(c0 + i) * R + r0 + tx] = (f16)tile[tx][i];
}

// ---------------- 256x256 GEMM, 1 barrier/phase, balanced MFMA ----------------
// A: [m][k] f16 (row stride K), B: [n][k] f16 (row stride K).
//  MODE 0: K=1024, u/v epilogue.  MODE 2: K=2048, p = u*(sq@v^T).
//  MODE 3: K=2048, out fp32 = acc*2^-34 + b_out.
template <int MODE>
__global__ __launch_bounds__(512, 2) void gemm256(
    const f16* __restrict__ Ag, const f16* __restrict__ Bg,
    float* __restrict__ F0, f16* __restrict__ O0, f16* __restrict__ O1,
    const f16* __restrict__ I0, const float* __restrict__ C0)
{
  constexpr int K  = (MODE == 0) ? H_DIM : 2048;
  constexpr int NT = K / 64;

  __shared__ f16 As[2][256][64];   // 64 KB
  __shared__ f16 Bs[2][256][64];   // 64 KB

  const int t    = threadIdx.x;
  const int w    = t >> 6;            // 0..7
  const int lane = t & 63;
  const int lo5  = lane & 31;
  const int hi   = lane >> 5;
  const int wm   = w >> 2;            // 0..1
  const int wn   = w & 3;             // 0..3

  // T1: bijective XCD swizzle (nwg % 8 == 0 for all modes)
  const int gx  = gridDim.x;
  const int nwg = gx * gridDim.y;
  const int lin = blockIdx.y * gx + blockIdx.x;
  const int cpx = nwg >> 3;
  const int wg  = (lin & 7) * cpx + (lin >> 3);
  const int n0  = (wg % gx) * 256;
  const int m0  = (wg / gx) * 256;
  const long z  = blockIdx.z;

  const f16* A = Ag + (MODE == 2 ? z * (long)S_LEN * S_LEN : 0);
  const f16* B = Bg + (MODE == 2 ? z * (long)E_DIM * S_LEN : 0);

  // stage one half-tile (128 rows x 64 k): 2 x gload16 per thread.
  // LDS dst linear; global column pre-swizzled:
  //   logical chunk = (lane&7) ^ (lane>>3) ^ (grp&1)   [= p ^ (r&7) ^ ((r>>3)&1)]
  auto stageA = [&](int bb, int half, int kt2) {
    const f16* g0 = A + (long)(m0 + half * 128) * K + kt2 * 64;
    f16* lb = &As[bb][half * 128][0];
#pragma unroll
    for (int j = 0; j < 2; j++) {
      int grp = (j << 3) + w;                       // 0..15
      int rl  = (grp << 3) + (lane >> 3);           // 0..127
      gload16(g0 + (long)rl * K + (((lane & 7) ^ (lane >> 3) ^ (grp & 1)) << 3),
              lb + (grp << 9));
    }
  };
  auto stageB = [&](int bb, int half, int kt2) {
    const f16* g0 = B + (long)(n0 + half * 128) * K + kt2 * 64;
    f16* lb = &Bs[bb][half * 128][0];
#pragma unroll
    for (int j = 0; j < 2; j++) {
      int grp = (j << 3) + w;
      int rl  = (grp << 3) + (lane >> 3);
      gload16(g0 + (long)rl * K + (((lane & 7) ^ (lane >> 3) ^ (grp & 1)) << 3),
              lb + (grp << 9));
    }
  };

  // acc[q][im]: q = ms*2 + ns; rows ms*128+wm*64+im*32, cols ns*128+wn*32
  f32x16 acc[4][2] = {};
  f16x8 a0[2][4], a1[2][4], b0[4], b1[4];

  const int swz = (lo5 & 7) ^ ((lo5 >> 3) & 1);   // reader row-swizzle term
  const int rA  = wm * 64 + lo5;
  const int rB  = wn * 32 + lo5;

  auto loadA0h = [&](int bb, int im) {
#pragma unroll
    for (int k = 0; k < 4; k++) {
      const int pc = ((((k << 1) + hi) ^ swz) << 3);
      a0[im][k] = *(const f16x8*)&As[bb][rA + im * 32][pc];
    }
  };
  auto loadA1h = [&](int bb, int im) {
#pragma unroll
    for (int k = 0; k < 4; k++) {
      const int pc = ((((k << 1) + hi) ^ swz) << 3);
      a1[im][k] = *(const f16x8*)&As[bb][128 + rA + im * 32][pc];
    }
  };
  auto loadB0 = [&](int bb) {
#pragma unroll
    for (int k = 0; k < 4; k++) {
      const int pc = ((((k << 1) + hi) ^ swz) << 3);
      b0[k] = *(const f16x8*)&Bs[bb][rB][pc];
    }
  };
  auto loadB1 = [&](int bb) {
#pragma unroll
    for (int k = 0; k < 4; k++) {
      const int pc = ((((k << 1) + hi) ^ swz) << 3);
      b1[k] = *(const f16x8*)&Bs[bb][128 + rB][pc];
    }
  };

#define MMA4(Q, IM, AV, BV) do {                                                 \
    _Pragma("unroll")                                                            \
    for (int k_ = 0; k_ < 4; k_++)                                               \
      acc[Q][IM] = __builtin_amdgcn_mfma_f32_32x32x16_f16(AV[k_], BV[k_],        \
                                                          acc[Q][IM], 0, 0, 0);  \
  } while (0)

  // prologue: stage tile0 (buf0) and tile1 (buf1) fully; wait tile0; barrier.
  stageA(0, 0, 0); stageA(0, 1, 0); stageB(0, 0, 0); stageB(0, 1, 0);
  stageA(1, 0, 1); stageA(1, 1, 1); stageB(1, 0, 1); stageB(1, 1, 1);
  asm volatile("s_waitcnt vmcnt(8)" ::: "memory");
  __builtin_amdgcn_s_barrier();

  for (int kt = 0; kt < NT; ++kt) {
    const int bf = kt & 1;
    const bool s2 = (kt + 2 < NT);

    // ---- P1: reads a0(im0), b0, a0(im1) [12]; MFMA acc00 [4]
    loadA0h(bf, 0); loadB0(bf); loadA0h(bf, 1);
    __builtin_amdgcn_s_setprio(1);
    MMA4(0, 0, a0[0], b0);
    __builtin_amdgcn_s_setprio(0);
    __builtin_amdgcn_s_barrier();

    // ---- P2: stage t+2:A0,B0; reads b1 [4]; MFMA acc01, acc10 [8]
    if (s2) { stageA(bf, 0, kt + 2); stageB(bf, 0, kt + 2); }
    loadB1(bf);
    __builtin_amdgcn_s_setprio(1);
    MMA4(0, 1, a0[1], b0);
    MMA4(1, 0, a0[0], b1);
    __builtin_amdgcn_s_setprio(0);
    __builtin_amdgcn_s_barrier();

    // ---- P3: stage t+2:B1; reads a1 [8]; MFMA acc11, acc20 [8]
    if (s2) stageB(bf, 1, kt + 2);
    loadA1h(bf, 0); loadA1h(bf, 1);
    __builtin_amdgcn_s_setprio(1);
    MMA4(1, 1, a0[1], b1);
    MMA4(2, 0, a1[0], b0);
    __builtin_amdgcn_s_setprio(0);
    __builtin_amdgcn_s_barrier();

    // ---- P4: stage t+2:A1; no reads; MFMA acc21, acc30, acc31 [12]; drain t+1
    if (s2) stageA(bf, 1, kt + 2);
    __builtin_amdgcn_s_setprio(1);
    MMA4(2, 1, a1[1], b0);
    MMA4(3, 0, a1[0], b1);
    MMA4(3, 1, a1[1], b1);
    __builtin_amdgcn_s_setprio(0);
    if (s2) { asm volatile("s_waitcnt vmcnt(8)" ::: "memory"); }
    else    { asm volatile("s_waitcnt vmcnt(0)" ::: "memory"); }
    __builtin_amdgcn_s_barrier();
  }
#undef MMA4

  // C/D (32x32): col = lane&31, row = (reg&3) + 8*(reg>>2) + 4*hi
#pragma unroll
  for (int q = 0; q < 4; q++) {
    const int ms = q >> 1;
    const int ns = q & 1;
#pragma unroll
    for (int im = 0; im < 2; im++) {
      const int gc    = n0 + ns * 128 + wn * 32 + lo5;
      const int rbase = m0 + ms * 128 + wm * 64 + im * 32 + (hi << 2);
      if (MODE == 0) {
        const float bias = C0[gc];
        if (n0 < E_DIM) {            // u region: fp16 row-major [M][E]
#pragma unroll
          for (int g = 0; g < 4; g++)
#pragma unroll
            for (int rr = 0; rr < 4; rr++) {
              int gr = rbase + (g << 3) + rr;
              O0[(long)gr * E_DIM + gc] = (f16)silu_f(acc[q][im][g * 4 + rr] + bias);
            }
        } else {                     // v region: fp16 transposed [b][e][s]
#pragma unroll
          for (int g = 0; g < 4; g++) {
            int gr0 = rbase + (g << 3);
            int b   = gr0 >> 11;
            int s0  = gr0 & (S_LEN - 1);
            f16x4 pk;
#pragma unroll
            for (int rr = 0; rr < 4; rr++) pk[rr] = (f16)silu_f(acc[q][im][g * 4 + rr] + bias);
            *(f16x4*)&O1[((long)b * E_DIM + (gc - E_DIM)) * S_LEN + s0] = pk;
          }
        }
      } else if (MODE == 2) {        // p = fp16(u * attn_v_scaled)
        const long rowoff = z * S_LEN;
#pragma unroll
        for (int g = 0; g < 4; g++)
#pragma unroll
          for (int rr = 0; rr < 4; rr++) {
            int gr = rbase + (g << 3) + rr;
            long idx = (rowoff + gr) * (long)E_DIM + gc;
            O0[idx] = (f16)((float)I0[idx] * acc[q][im][g * 4 + rr]);
          }
      } else {                       // MODE 3: out = acc*2^-34 + b_out (fp32)
        const float bias = C0[gc];
#pragma unroll
        for (int g = 0; g < 4; g++)
#pragma unroll
          for (int rr = 0; rr < 4; rr++) {
            int gr = rbase + (g << 3) + rr;
            F0[(long)gr * H_DIM + gc] = acc[q][im][g * 4 + rr] * (1.0f / 17179869184.0f) + bias;
          }
      }
    }
  }
}

// ---------------- old 128x128 kernel (modes 1 and 4 only) ----------------
template <int MODE>
__global__ __launch_bounds__(256) void mfma_gemm(
    const f16* __restrict__ Ag, const f16* __restrict__ Bg,
    float* __restrict__ F0, f16* __restrict__ H0, const f16* __restrict__ H1,
    f16* __restrict__ H2, f16* __restrict__ H3,
    const float* __restrict__ C0, const float* __restrict__ C1,
    const float* __restrict__ C2)
{
  constexpr int K   = (MODE == 1) ? SD : H_DIM;
  constexpr int LDA = K, LDB = K;

  __shared__ f16 As[2][128][32];
  __shared__ f16 Bs[2][128][32];

  const int t    = threadIdx.x;
  const int w    = t >> 6;
  const int lane = t & 63;
  const int lo5  = lane & 31;
  const int hi   = lane >> 5;
  const int wy   = w >> 1, wx = w & 1;
  const int m0   = blockIdx.y * 128;
  const int n0   = blockIdx.x * 128;
  const long z   = blockIdx.z;

  const f16* A = Ag + (MODE == 1 ? z * (long)S_LEN * SD : 0);
  const f16* B = Bg + (MODE == 1 ? z * (long)S_LEN * SD : 0);

  const int srow = lane >> 2;
  const int scol = (((lane & 3) ^ ((srow >> 1) & 3))) * 8;
  const int rsw  = (lo5 >> 1) & 3;

  f32x16 acc[2][2] = {};

  for (int k0 = 0; k0 < K; k0 += 64) {
#pragma unroll
    for (int h = 0; h < 2; h++)
#pragma unroll
      for (int g16 = 0; g16 < 2; g16++) {
        const int r = (w << 5) + (g16 << 4);
        gload16(A + (long)(m0 + r + srow) * LDA + k0 + (h << 5) + scol, &As[h][r][0]);
        gload16(B + (long)(n0 + r + srow) * LDB + k0 + (h << 5) + scol, &Bs[h][r][0]);
      }
    __syncthreads();

#pragma unroll
    for (int ks = 0; ks < 4; ks++) {
      const int h  = ks >> 1;
      const int cl = ((ks & 1) << 1) + hi;
      const int kc = (cl ^ rsw) << 3;
      f16x8 av[2], bv[2];
#pragma unroll
      for (int i = 0; i < 2; i++)
        av[i] = *(const f16x8*)&As[h][(wy << 6) + (i << 5) + lo5][kc];
#pragma unroll
      for (int j = 0; j < 2; j++)
        bv[j] = *(const f16x8*)&Bs[h][(wx << 6) + (j << 5) + lo5][kc];
#pragma unroll
      for (int i = 0; i < 2; i++)
#pragma unroll
        for (int j = 0; j < 2; j++)
          acc[i][j] = __builtin_amdgcn_mfma_f32_32x32x16_f16(av[i], bv[j], acc[i][j], 0, 0, 0);
    }
    __syncthreads();
  }

  const int rb0 = m0 + (wy << 6) + (hi << 2);
  const int cb0 = n0 + (wx << 6) + lo5;

  if (MODE == 4) {                    // q,k from base cols (N=128)
#pragma unroll
    for (int i = 0; i < 2; i++)
#pragma unroll
      for (int j = 0; j < 2; j++) {
        int jj = cb0 + (j << 5);
        float bias = C0[jj];
        float g0 = C1[jj], g1 = C1[SD + jj];
        float be0 = C2[jj], be1 = C2[SD + jj];
#pragma unroll
        for (int g = 0; g < 4; g++)
#pragma unroll
          for (int rr = 0; rr < 4; rr++) {
            int gr = rb0 + (i << 5) + (g << 3) + rr;
            float s = silu_f(acc[i][j][g * 4 + rr] + bias);
            H2[(long)gr * SD + jj] = (f16)(s * g0 + be0);
            H3[(long)gr * SD + jj] = (f16)(s * g1 + be1);
          }
      }
  } else {                            // MODE 1: sq = (relu(q·k)*64)^2
#pragma unroll
    for (int i = 0; i < 2; i++)
#pragma unroll
      for (int j = 0; j < 2; j++) {
        int gc = cb0 + (j << 5);
#pragma unroll
        for (int g = 0; g < 4; g++)
#pragma unroll
          for (int rr = 0; rr < 4; rr++) {
            int gr = rb0 + (i << 5) + (g << 3) + rr;
            float tv = fmaxf(acc[i][j][g * 4 + rr], 0.f) * 64.f;
            H0[z * (long)S_LEN * S_LEN + (long)gr * S_LEN + gc] = (f16)(tv * tv);
          }
      }
  }
}

extern "C" void kernel_launch(void* const* d_in, const int* in_sizes, int n_in,
                              void* d_out, int out_size, void* d_ws, size_t ws_size,
                              hipStream_t stream) {
  const float* X     = (const float*)d_in[0];
  const float* W_uv  = (const float*)d_in[1];
  const float* b_uv  = (const float*)d_in[2];
  const float* gamma = (const float*)d_in[3];
  const float* beta  = (const float*)d_in[4];
  const float* W_out = (const float*)d_in[5];
  const float* b_out = (const float*)d_in[6];
  float* out = (float*)d_out;

  char* wp = (char*)d_ws;
  f16* Xh   = (f16*)wp; wp += (long)M_TOT * H_DIM * 2;
  f16* Wuvt = (f16*)wp; wp += (long)F_DIM * H_DIM * 2;
  f16* Wt   = (f16*)wp; wp += (long)H_DIM * E_DIM * 2;
  f16* u    = (f16*)wp; wp += (long)M_TOT * E_DIM * 2;
  f16* vt   = (f16*)wp; wp += (long)M_TOT * E_DIM * 2;
  f16* qh   = (f16*)wp; wp += (long)M_TOT * SD * 2;
  f16* kh   = (f16*)wp; wp += (long)M_TOT * SD * 2;
  f16* sq   = (f16*)wp; wp += (long)B_SZ * S_LEN * S_LEN * 2;
  f16* p    = (f16*)wp; wp += (long)M_TOT * E_DIM * 2;

  // prep
  cast_f16_k<<<(M_TOT * H_DIM) / (256 * 4), 256, 0, stream>>>(X, Xh, (long)M_TOT * H_DIM);
  transpose_cast_k<<<dim3(F_DIM / 32, H_DIM / 32), 256, 0, stream>>>(W_uv, Wuvt, H_DIM, F_DIM);
  transpose_cast_k<<<dim3(H_DIM / 32, E_DIM / 32), 256, 0, stream>>>(W_out, Wt, E_DIM, H_DIM);

  // u, v_t  (M=8192, N=4096, K=1024)
  gemm256<0><<<dim3(2 * E_DIM / 256, M_TOT / 256, 1), 512, 0, stream>>>(
      Xh, Wuvt, nullptr, u, vt, nullptr, b_uv);

  // q, k (base 128 cols)
  mfma_gemm<4><<<dim3(1, M_TOT / 128, 1), 256, 0, stream>>>(
      Xh, Wuvt + (long)2 * E_DIM * H_DIM, nullptr, nullptr, nullptr, qh, kh,
      b_uv + 2 * E_DIM, gamma, beta);

  // sq = (relu(q@k^T)*2^6)^2
  mfma_gemm<1><<<dim3(S_LEN / 128, S_LEN / 128, B_SZ), 256, 0, stream>>>(
      qh, kh, nullptr, sq, nullptr, nullptr, nullptr, nullptr, nullptr, nullptr);

  // p = u * (sq @ v)  (M=2048/batch, N=2048, K=2048)
  gemm256<2><<<dim3(E_DIM / 256, S_LEN / 256, B_SZ), 512, 0, stream>>>(
      sq, vt, nullptr, p, nullptr, u, nullptr);

  // out = p @ W_out * 2^-34 + b_out  (M=8192, N=1024, K=2048)
  gemm256<3><<<dim3(H_DIM / 256, M_TOT / 256, 1), 512, 0, stream>>>(
      p, Wt, out, nullptr, nullptr, nullptr, b_out);
}